// Round 2
// baseline (1431.153 us; speedup 1.0000x reference)
//
#include <hip/hip_runtime.h>
#include <stdint.h>

// PointerNet: B=8, F=4000, S=512, E=H=128, TOPK=8, USE_MASK=1, EPS=1e-4
#define S_    512
#define B_    8
#define F_    4000
#define E_    128
#define H_    128
#define TOPK_ 8
#define S2_   (S_*S_)        // 262144
#define BSS_  (B_*S2_)       // 2097152

// ---------------- threefry2x32 (exact JAX semantics) ----------------
__device__ __forceinline__ void tf2x32(uint32_t k0, uint32_t k1, uint32_t& x0, uint32_t& x1) {
  uint32_t k2 = k0 ^ k1 ^ 0x1BD11BDAu;
  x0 += k0; x1 += k1;
#define TFR(r) { x0 += x1; x1 = (x1 << (r)) | (x1 >> (32 - (r))); x1 ^= x0; }
  TFR(13) TFR(15) TFR(26) TFR(6)
  x0 += k1; x1 += k2 + 1u;
  TFR(17) TFR(29) TFR(16) TFR(24)
  x0 += k2; x1 += k0 + 2u;
  TFR(13) TFR(15) TFR(26) TFR(6)
  x0 += k0; x1 += k1 + 3u;
  TFR(17) TFR(29) TFR(16) TFR(24)
  x0 += k1; x1 += k2 + 4u;
  TFR(13) TFR(15) TFR(26) TFR(6)
  x0 += k2; x1 += k0 + 5u;
#undef TFR
}

// jax_threefry_partitionable=True (default in modern JAX):
// split(key,n)[i] = threefry2x32(key, x0=hi32(i)=0, x1=lo32(i)=i) -> (x0out, x1out)
__device__ __forceinline__ void splitkey(int i, uint32_t& k0, uint32_t& k1) {
  uint32_t x0 = 0u, x1 = (uint32_t)i;
  tf2x32(0u, 42u, x0, x1);   // key(42) = (0, 42)
  k0 = x0; k1 = x1;
}

// random_bits(key, 32, shape)[m] = bits1 ^ bits2 with (x0,x1)=(0,m)
__device__ __forceinline__ uint32_t randbits32(uint32_t k0, uint32_t k1, uint32_t m) {
  uint32_t x0 = 0u, x1 = m;
  tf2x32(k0, k1, x0, x1);
  return x0 ^ x1;
}

// ---------------- stage A: embedded = tanh(inputs^T @ embedding), f64 accum ----------------
__global__ __launch_bounds__(256) void embed_kernel(const float* __restrict__ inputs,
                                                    const float* __restrict__ embedding,
                                                    double* __restrict__ emb64) {
  const int b  = blockIdx.x >> 5;          // 32 blocks per batch
  const int s0 = (blockIdx.x & 31) << 4;   // 16 s per block
  const int t  = threadIdx.x;
  const int sl = t >> 4;                   // owned s (0..15)
  const int eg = t & 15;                   // e-group: e = eg*8 + j
  __shared__ float inA[16][16];
  double acc[8];
#pragma unroll
  for (int j = 0; j < 8; j++) acc[j] = 0.0;
  for (int f0 = 0; f0 < F_; f0 += 16) {
    __syncthreads();
    inA[t >> 4][t & 15] = inputs[(size_t)(b*F_ + f0 + (t >> 4))*S_ + s0 + (t & 15)];
    __syncthreads();
#pragma unroll
    for (int k = 0; k < 16; k++) {
      double a = (double)inA[k][sl];
      const float4* ep = (const float4*)(embedding + (size_t)(f0 + k)*E_ + eg*8);
      float4 w0 = ep[0], w1 = ep[1];
      acc[0] += a * (double)w0.x; acc[1] += a * (double)w0.y;
      acc[2] += a * (double)w0.z; acc[3] += a * (double)w0.w;
      acc[4] += a * (double)w1.x; acc[5] += a * (double)w1.y;
      acc[6] += a * (double)w1.z; acc[7] += a * (double)w1.w;
    }
  }
  double* op = emb64 + (size_t)(b*S_ + s0 + sl)*E_ + eg*8;
#pragma unroll
  for (int j = 0; j < 8; j++) op[j] = tanh(acc[j]);
}

// ---------------- stage B: logits = emb @ W[i] + b; probs = clip(sigmoid) ----------------
__global__ __launch_bounds__(256) void logits_kernel(const double* __restrict__ emb64,
                                                     const float* __restrict__ W,
                                                     const float* __restrict__ bias,
                                                     double* __restrict__ p64,
                                                     float* __restrict__ p32) {
  const int i  = blockIdx.x >> 3;
  const int o0 = (blockIdx.x & 7) << 6;
  const int t  = threadIdx.x;
  const int o  = o0 + (t & 63);
  const int bg = t >> 6;                  // wave id: batches bg and bg+4
  __shared__ double eL[8][128];
#pragma unroll
  for (int k = 0; k < 4; k++) {
    int q = t + k*256;
    eL[q >> 7][q & 127] = emb64[(size_t)((q >> 7)*S_ + i)*E_ + (q & 127)];
  }
  __syncthreads();
  double a0 = 0.0, a1 = 0.0;
  const float* Wp = W + (size_t)i*H_*S_ + o;
  for (int h = 0; h < H_; h++) {
    double w = (double)Wp[(size_t)h*S_];
    a0 += eL[bg][h]     * w;
    a1 += eL[bg + 4][h] * w;
  }
  double bd = (double)bias[i*S_ + o];
  double q0 = 1.0 / (1.0 + exp(-(a0 + bd)));
  double q1 = 1.0 / (1.0 + exp(-(a1 + bd)));
  q0 = fmin(fmax(q0, 1e-4), 1.0 - 1e-4);
  q1 = fmin(fmax(q1, 1e-4), 1.0 - 1e-4);
  size_t i0 = (size_t)(bg*S_ + i)*S_ + o;
  size_t i1 = (size_t)((bg + 4)*S_ + i)*S_ + o;
  p64[i0] = q0; p64[i1] = q1;
  p32[i0] = (float)q0; p32[i1] = (float)q1;
}

// ---------------- stage C: per-(step,b): bernoulli bits & top-8 keep, bit-packed ----------------
__global__ __launch_bounds__(64) void samppre_kernel(const double* __restrict__ p64,
                                                     float* __restrict__ outbase) {
  const int i = blockIdx.x >> 3;
  const int b = blockIdx.x & 7;
  const int l = threadIdx.x;
  unsigned long long* samp_pre =
      (unsigned long long*)(outbase + 3*(size_t)BSS_ + (size_t)b*S2_);  // 32KB/b, dead emb zone
  uint32_t k0, k1;
  splitkey(i, k0, k1);
  double pv[8]; bool sb[8]; bool usedk[8]; bool keep[8];
#pragma unroll
  for (int w = 0; w < 8; w++) {
    int c = (w << 6) + l;
    uint32_t m = (uint32_t)(b*S_ + c);      // flat index into (B,S)
    uint32_t bits = randbits32(k0, k1, m);
    float uf = __uint_as_float((bits >> 9) | 0x3f800000u) - 1.0f;
    double p = p64[(size_t)(b*S_ + i)*S_ + c];
    pv[w] = p;
    sb[w] = ((double)uf < p) && (c != i);
    usedk[w] = false; keep[w] = false;
  }
  for (int r = 0; r < TOPK_; r++) {
    double bp = -1.0; int bc = 0x7fffffff;
#pragma unroll
    for (int w = 0; w < 8; w++) {
      int c = (w << 6) + l;
      if (!usedk[w] && (pv[w] > bp || (pv[w] == bp && c < bc))) { bp = pv[w]; bc = c; }
    }
#pragma unroll
    for (int d = 1; d < 64; d <<= 1) {
      double op = __shfl_xor(bp, d);
      int    oc = __shfl_xor(bc, d);
      if (op > bp || (op == bp && oc < bc)) { bp = op; bc = oc; }
    }
    if ((bc & 63) == l) { usedk[bc >> 6] = true; keep[bc >> 6] = true; }
  }
#pragma unroll
  for (int w = 0; w < 8; w++) {
    unsigned long long word = __ballot((int)(sb[w] && keep[w]));
    if (l == 0) samp_pre[i*8 + w] = word;
  }
}

// ---------------- stage D: sequential acyclic-mask scan (1 block per batch) ----------------
// Ancestor-set representation: Aw[w][c] = bits a in [64w,64w+64) of "a is ancestor of c".
__global__ __launch_bounds__(256) void scan_kernel(float* outbase) {
  const int b = blockIdx.x;
  const int t = threadIdx.x;
  const int wv = t >> 6, l = t & 63;
  const unsigned long long* samp_pre =
      (const unsigned long long*)(outbase + 3*(size_t)BSS_ + (size_t)b*S2_);
  float* out_idx  = outbase + 2*(size_t)BSS_ + (size_t)b*S2_;
  float* out_mask = outbase + 3*(size_t)BSS_ + (size_t)b*S2_;  // overwrites samp_pre zone (after use)
  __shared__ unsigned long long Aw[8][S_];
  __shared__ unsigned long long rowW[8], sampW[8], colW[8];
  __shared__ int sel[16];
  __shared__ int nsel;
  for (int q = t; q < 8*S_; q += 256) (&Aw[0][0])[q] = 0ULL;
  __syncthreads();
  const int c1 = t, c2 = t + 256;
  for (int idx = 0; idx < S_; idx++) {
    const int iw = idx >> 6, ib = idx & 63;
    // P1: row = descendants of idx (D(idx)[c] = bit idx of A(c))
    unsigned long long bal1 = __ballot((int)((Aw[iw][c1] >> ib) & 1ULL));
    unsigned long long bal2 = __ballot((int)((Aw[iw][c2] >> ib) & 1ULL));
    if (l == 0) { rowW[wv] = bal1; rowW[wv + 4] = bal2; }
    __syncthreads();
    // P2 (wave 0): samp = samp_pre & ~row; anc = OR A(c) over selected; col = A(idx)|samp|anc
    if (wv == 0) {
      if (l == 0) nsel = 0;
      unsigned long long sw = 0ULL;
      if (l < 8) {
        sw = samp_pre[idx*8 + l] & ~rowW[l];
        sampW[l] = sw;
      }
      if (l < 8) {
        unsigned long long x = sw;
        while (x) {
          int bit  = __builtin_ctzll(x);
          int slot = atomicAdd(&nsel, 1);
          sel[slot] = (l << 6) + bit;
          x &= x - 1ULL;
        }
      }
      int n = nsel;
      int j = l >> 3, w = l & 7;
      unsigned long long av = 0ULL;
      if (j < n) av = Aw[w][sel[j]];
      av |= __shfl_xor(av, 8);
      av |= __shfl_xor(av, 16);
      av |= __shfl_xor(av, 32);
      if (l < 8) {
        unsigned long long col = Aw[l][idx] | sampW[l] | av;
        Aw[l][idx] = col;
        colW[l] = col;
      }
      // emit prev_idxs row (floats 0/1) for this step
      float* orow = out_idx + (size_t)idx*S_;
#pragma unroll
      for (int w2 = 0; w2 < 8; w2++) {
        unsigned long long xw = __shfl(sw, w2);
        orow[(w2 << 6) + l] = (float)((xw >> l) & 1ULL);
      }
    }
    __syncthreads();
    // P3: propagate: for c in row: A(c) |= col
    bool rb1 = (bal1 >> l) & 1ULL;
    bool rb2 = (bal2 >> l) & 1ULL;
    if (rb1) {
#pragma unroll
      for (int w = 0; w < 8; w++) Aw[w][c1] |= colW[w];
    }
    if (rb2) {
#pragma unroll
      for (int w = 0; w < 8; w++) Aw[w][c2] |= colW[w];
    }
    __syncthreads();
  }
  // dump final mask as floats
  for (int q = t; q < S2_; q += 256) {
    int a = q >> 9, c = q & (S_ - 1);
    out_mask[q] = (float)((Aw[a >> 6][c] >> (a & 63)) & 1ULL);
  }
}

extern "C" void kernel_launch(void* const* d_in, const int* in_sizes, int n_in,
                              void* d_out, int out_size, void* d_ws, size_t ws_size,
                              hipStream_t stream) {
  const float* inputs    = (const float*)d_in[0];
  const float* embedding = (const float*)d_in[1];
  const float* W         = (const float*)d_in[2];
  const float* bias      = (const float*)d_in[3];
  // d_in[4] = offset_prob: unused by the reference.
  float* out = (float*)d_out;
  // scratch carved from dead d_out regions (no d_ws dependence):
  //  p64   in [BSS, 3BSS)  (regions 1-2) — dead after samppre
  //  emb64 in [3BSS, 3BSS+1M f32) (region 3 head) — dead after logits
  //  samp_pre per-b 32KB at region-3 b-zones — each block b overwrites its own zone last
  double* emb64 = (double*)(out + 3*(size_t)BSS_);
  double* p64   = (double*)(out + (size_t)BSS_);

  embed_kernel  <<<256,  256, 0, stream>>>(inputs, embedding, emb64);
  logits_kernel <<<4096, 256, 0, stream>>>(emb64, W, bias, p64, out);
  samppre_kernel<<<4096, 64,  0, stream>>>(p64, out);
  scan_kernel   <<<8,    256, 0, stream>>>(out);
  hipMemsetAsync(out + (size_t)BSS_, 0, (size_t)BSS_ * sizeof(float), stream);  // prev_probs_2 = 0
}

// Round 3
// 1092.256 us; speedup vs baseline: 1.3103x; 1.3103x over previous
//
#include <hip/hip_runtime.h>
#include <stdint.h>

// PointerNet: B=8, F=4000, S=512, E=H=128, TOPK=8, USE_MASK=1, EPS=1e-4
#define S_    512
#define B_    8
#define F_    4000
#define E_    128
#define H_    128
#define TOPK_ 8
#define S2_   (S_*S_)        // 262144
#define BSS_  (B_*S2_)       // 2097152
#define BSE_  (B_*S_*E_)     // 524288 (f64 elements per embed partial = 4MB)
#define NCHUNK_ 8

// ---------------- threefry2x32 (exact JAX semantics) ----------------
__device__ __forceinline__ void tf2x32(uint32_t k0, uint32_t k1, uint32_t& x0, uint32_t& x1) {
  uint32_t k2 = k0 ^ k1 ^ 0x1BD11BDAu;
  x0 += k0; x1 += k1;
#define TFR(r) { x0 += x1; x1 = (x1 << (r)) | (x1 >> (32 - (r))); x1 ^= x0; }
  TFR(13) TFR(15) TFR(26) TFR(6)
  x0 += k1; x1 += k2 + 1u;
  TFR(17) TFR(29) TFR(16) TFR(24)
  x0 += k2; x1 += k0 + 2u;
  TFR(13) TFR(15) TFR(26) TFR(6)
  x0 += k0; x1 += k1 + 3u;
  TFR(17) TFR(29) TFR(16) TFR(24)
  x0 += k1; x1 += k2 + 4u;
  TFR(13) TFR(15) TFR(26) TFR(6)
  x0 += k2; x1 += k0 + 5u;
#undef TFR
}

// jax_threefry_partitionable=True (modern JAX default):
// split(key,n)[i] = threefry2x32(key, x0=0, x1=i) -> (x0out, x1out)
__device__ __forceinline__ void splitkey(int i, uint32_t& k0, uint32_t& k1) {
  uint32_t x0 = 0u, x1 = (uint32_t)i;
  tf2x32(0u, 42u, x0, x1);   // key(42) = (0, 42)
  k0 = x0; k1 = x1;
}

// random_bits(key, 32, shape)[m] = x0out ^ x1out with (x0,x1)=(0,m)
__device__ __forceinline__ uint32_t randbits32(uint32_t k0, uint32_t k1, uint32_t m) {
  uint32_t x0 = 0u, x1 = m;
  tf2x32(k0, k1, x0, x1);
  return x0 ^ x1;
}

// ---------------- stage A: split-K partial f64 GEMM: part[c] += inputs^T @ embedding ----------------
// grid: chunk(8) x b(8) x stile(32) = 2048 blocks -> 8 blocks/CU, full occupancy
__global__ __launch_bounds__(256) void embed_kernel(const float* __restrict__ inputs,
                                                    const float* __restrict__ embedding,
                                                    double* __restrict__ part) {
  const int c  = blockIdx.x >> 8;            // F-chunk 0..7
  const int b  = (blockIdx.x >> 5) & 7;
  const int s0 = (blockIdx.x & 31) << 4;     // 16 s per block
  const int fbeg = c << 9;
  const int fend = (fbeg + 512 < F_) ? fbeg + 512 : F_;   // 512,...,512,416 (all %16==0)
  const int t  = threadIdx.x;
  const int sl = t >> 4;                     // owned s (0..15)
  const int eg = t & 15;                     // e-group: e = eg*8 + j
  __shared__ float inA[16][16];
  double acc[8];
#pragma unroll
  for (int j = 0; j < 8; j++) acc[j] = 0.0;
  for (int f0 = fbeg; f0 < fend; f0 += 16) {
    __syncthreads();
    inA[t >> 4][t & 15] = inputs[(size_t)(b*F_ + f0 + (t >> 4))*S_ + s0 + (t & 15)];
    __syncthreads();
#pragma unroll
    for (int k = 0; k < 16; k++) {
      double a = (double)inA[k][sl];
      const float4* ep = (const float4*)(embedding + (size_t)(f0 + k)*E_ + eg*8);
      float4 w0 = ep[0], w1 = ep[1];
      acc[0] += a * (double)w0.x; acc[1] += a * (double)w0.y;
      acc[2] += a * (double)w0.z; acc[3] += a * (double)w0.w;
      acc[4] += a * (double)w1.x; acc[5] += a * (double)w1.y;
      acc[6] += a * (double)w1.z; acc[7] += a * (double)w1.w;
    }
  }
  double* op = part + (size_t)c*BSE_ + (size_t)(b*S_ + s0 + sl)*E_ + eg*8;
#pragma unroll
  for (int j = 0; j < 8; j++) op[j] = acc[j];
}

// sum 8 partials + tanh -> emb64 (emb64 aliases part[6]; per-thread read-all-then-write-own is safe)
__global__ __launch_bounds__(256) void reduce_tanh_kernel(float* __restrict__ outbase) {
  const size_t j = (size_t)blockIdx.x*256 + threadIdx.x;   // 0..BSE_-1
  const double* part = (const double*)outbase;
  double s = 0.0;
#pragma unroll
  for (int c = 0; c < NCHUNK_; c++) s += part[(size_t)c*BSE_ + j];
  double* emb64 = (double*)(outbase + 3*(size_t)BSS_);
  emb64[j] = tanh(s);
}

// ---------------- stage B: logits = emb @ W[i] + b; probs = clip(sigmoid) ----------------
__global__ __launch_bounds__(256) void logits_kernel(const double* __restrict__ emb64,
                                                     const float* __restrict__ W,
                                                     const float* __restrict__ bias,
                                                     double* __restrict__ p64,
                                                     float* __restrict__ p32) {
  const int i  = blockIdx.x >> 3;
  const int o0 = (blockIdx.x & 7) << 6;
  const int t  = threadIdx.x;
  const int o  = o0 + (t & 63);
  const int bg = t >> 6;                  // wave id: batches bg and bg+4
  __shared__ double eL[8][128];
#pragma unroll
  for (int k = 0; k < 4; k++) {
    int q = t + k*256;
    eL[q >> 7][q & 127] = emb64[(size_t)((q >> 7)*S_ + i)*E_ + (q & 127)];
  }
  __syncthreads();
  double a0 = 0.0, a1 = 0.0;
  const float* Wp = W + (size_t)i*H_*S_ + o;
  for (int h = 0; h < H_; h++) {
    double w = (double)Wp[(size_t)h*S_];
    a0 += eL[bg][h]     * w;
    a1 += eL[bg + 4][h] * w;
  }
  double bd = (double)bias[i*S_ + o];
  double q0 = 1.0 / (1.0 + exp(-(a0 + bd)));
  double q1 = 1.0 / (1.0 + exp(-(a1 + bd)));
  q0 = fmin(fmax(q0, 1e-4), 1.0 - 1e-4);
  q1 = fmin(fmax(q1, 1e-4), 1.0 - 1e-4);
  size_t i0 = (size_t)(bg*S_ + i)*S_ + o;
  size_t i1 = (size_t)((bg + 4)*S_ + i)*S_ + o;
  p64[i0] = q0; p64[i1] = q1;
  p32[i0] = (float)q0; p32[i1] = (float)q1;
}

// ---------------- stage C: per-(step,b): bernoulli bits & top-8 keep, bit-packed ----------------
__global__ __launch_bounds__(64) void samppre_kernel(const double* __restrict__ p64,
                                                     float* __restrict__ outbase) {
  const int i = blockIdx.x >> 3;
  const int b = blockIdx.x & 7;
  const int l = threadIdx.x;
  unsigned long long* samp_pre =
      (unsigned long long*)(outbase + 3*(size_t)BSS_ + (size_t)b*S2_);  // 32KB/b, dead emb zone
  uint32_t k0, k1;
  splitkey(i, k0, k1);
  double pv[8]; bool sb[8]; bool usedk[8]; bool keep[8];
#pragma unroll
  for (int w = 0; w < 8; w++) {
    int c = (w << 6) + l;
    uint32_t m = (uint32_t)(b*S_ + c);      // flat index into (B,S)
    uint32_t bits = randbits32(k0, k1, m);
    float uf = __uint_as_float((bits >> 9) | 0x3f800000u) - 1.0f;
    double p = p64[(size_t)(b*S_ + i)*S_ + c];
    pv[w] = p;
    sb[w] = ((double)uf < p) && (c != i);
    usedk[w] = false; keep[w] = false;
  }
  for (int r = 0; r < TOPK_; r++) {
    double bp = -1.0; int bc = 0x7fffffff;
#pragma unroll
    for (int w = 0; w < 8; w++) {
      int c = (w << 6) + l;
      if (!usedk[w] && (pv[w] > bp || (pv[w] == bp && c < bc))) { bp = pv[w]; bc = c; }
    }
#pragma unroll
    for (int d = 1; d < 64; d <<= 1) {
      double op = __shfl_xor(bp, d);
      int    oc = __shfl_xor(bc, d);
      if (op > bp || (op == bp && oc < bc)) { bp = op; bc = oc; }
    }
    if ((bc & 63) == l) { usedk[bc >> 6] = true; keep[bc >> 6] = true; }
  }
#pragma unroll
  for (int w = 0; w < 8; w++) {
    unsigned long long word = __ballot((int)(sb[w] && keep[w]));
    if (l == 0) samp_pre[i*8 + w] = word;
  }
}

// ---------------- stage D: sequential acyclic-mask scan (1 block per batch) ----------------
// Ancestor-set representation: Aw[w][c] = bits a in [64w,64w+64) of "a is ancestor of c".
__global__ __launch_bounds__(256) void scan_kernel(float* outbase) {
  const int b = blockIdx.x;
  const int t = threadIdx.x;
  const int wv = t >> 6, l = t & 63;
  const unsigned long long* samp_pre =
      (const unsigned long long*)(outbase + 3*(size_t)BSS_ + (size_t)b*S2_);
  float* out_idx  = outbase + 2*(size_t)BSS_ + (size_t)b*S2_;
  float* out_mask = outbase + 3*(size_t)BSS_ + (size_t)b*S2_;  // overwrites samp_pre zone (after use)
  __shared__ unsigned long long Aw[8][S_];
  __shared__ unsigned long long rowW[8], sampW[8], colW[8];
  __shared__ int sel[16];
  __shared__ int nsel;
  for (int q = t; q < 8*S_; q += 256) (&Aw[0][0])[q] = 0ULL;
  __syncthreads();
  const int c1 = t, c2 = t + 256;
  for (int idx = 0; idx < S_; idx++) {
    const int iw = idx >> 6, ib = idx & 63;
    // P1: row = descendants of idx (D(idx)[c] = bit idx of A(c))
    unsigned long long bal1 = __ballot((int)((Aw[iw][c1] >> ib) & 1ULL));
    unsigned long long bal2 = __ballot((int)((Aw[iw][c2] >> ib) & 1ULL));
    if (l == 0) { rowW[wv] = bal1; rowW[wv + 4] = bal2; }
    __syncthreads();
    // P2 (wave 0): samp = samp_pre & ~row; anc = OR A(c) over selected; col = A(idx)|samp|anc
    if (wv == 0) {
      if (l == 0) nsel = 0;
      unsigned long long sw = 0ULL;
      if (l < 8) {
        sw = samp_pre[idx*8 + l] & ~rowW[l];
        sampW[l] = sw;
      }
      if (l < 8) {
        unsigned long long x = sw;
        while (x) {
          int bit  = __builtin_ctzll(x);
          int slot = atomicAdd(&nsel, 1);
          sel[slot] = (l << 6) + bit;
          x &= x - 1ULL;
        }
      }
      int n = nsel;
      int j = l >> 3, w = l & 7;
      unsigned long long av = 0ULL;
      if (j < n) av = Aw[w][sel[j]];
      av |= __shfl_xor(av, 8);
      av |= __shfl_xor(av, 16);
      av |= __shfl_xor(av, 32);
      if (l < 8) {
        unsigned long long col = Aw[l][idx] | sampW[l] | av;
        Aw[l][idx] = col;
        colW[l] = col;
      }
      // emit prev_idxs row (floats 0/1) for this step
      float* orow = out_idx + (size_t)idx*S_;
#pragma unroll
      for (int w2 = 0; w2 < 8; w2++) {
        unsigned long long xw = __shfl(sw, w2);
        orow[(w2 << 6) + l] = (float)((xw >> l) & 1ULL);
      }
    }
    __syncthreads();
    // P3: propagate: for c in row: A(c) |= col
    bool rb1 = (bal1 >> l) & 1ULL;
    bool rb2 = (bal2 >> l) & 1ULL;
    if (rb1) {
#pragma unroll
      for (int w = 0; w < 8; w++) Aw[w][c1] |= colW[w];
    }
    if (rb2) {
#pragma unroll
      for (int w = 0; w < 8; w++) Aw[w][c2] |= colW[w];
    }
    __syncthreads();
  }
  // dump final mask as floats
  for (int q = t; q < S2_; q += 256) {
    int a = q >> 9, c = q & (S_ - 1);
    out_mask[q] = (float)((Aw[a >> 6][c] >> (a & 63)) & 1ULL);
  }
}

extern "C" void kernel_launch(void* const* d_in, const int* in_sizes, int n_in,
                              void* d_out, int out_size, void* d_ws, size_t ws_size,
                              hipStream_t stream) {
  const float* inputs    = (const float*)d_in[0];
  const float* embedding = (const float*)d_in[1];
  const float* W         = (const float*)d_in[2];
  const float* bias      = (const float*)d_in[3];
  // d_in[4] = offset_prob: unused by the reference.
  float* out = (float*)d_out;
  // scratch timeline (all in d_out, no d_ws dependence):
  //  [t0] embed partials: 8 x 4MB f64 = ALL 32MB of d_out
  //  [t1] reduce_tanh: emb64 (4MB) at region-3 head (aliases part[6]; read-then-write safe)
  //  [t2] logits: reads emb64; writes p64 (regions 1-2, 16MB) + p32 (region 0) — partials dead
  //  [t3] samppre: reads p64; writes samp_pre (32KB per b at region-3 b-zones) — emb64 dead
  //  [t4] scan: reads samp_pre; writes out_idx (region 2; p64 dead) + out_mask (region 3)
  //  [t5] memset region 1 (prev_probs_2 = 0)
  double* part  = (double*)out;
  double* emb64 = (double*)(out + 3*(size_t)BSS_);
  double* p64   = (double*)(out + (size_t)BSS_);

  embed_kernel      <<<2048, 256, 0, stream>>>(inputs, embedding, part);
  reduce_tanh_kernel<<<2048, 256, 0, stream>>>(out);
  logits_kernel     <<<4096, 256, 0, stream>>>(emb64, W, bias, p64, out);
  samppre_kernel    <<<4096, 64,  0, stream>>>(p64, out);
  scan_kernel       <<<8,    256, 0, stream>>>(out);
  hipMemsetAsync(out + (size_t)BSS_, 0, (size_t)BSS_ * sizeof(float), stream);  // prev_probs_2 = 0
}